// Round 7
// baseline (430.871 us; speedup 1.0000x reference)
//
#include <hip/hip_runtime.h>
#include <math.h>

// N=32768, M=4096, H=768 fp32.
// out[0..768)=fact_, out[768..1536)=elements_p_.
// Reassociation: (X@W)@y^T == X@(W@y^T) -> matvecs only, never a GEMM.
// R6 post-mortem: single-block tails (combine + v matvec) are latency-bound
// gathers (~35 GB/s effective) -> 76us in k_ep. R7: TWO graph nodes; inside
// k_mega all cross-phase deps use arrive(threadfence+atomicAdd, R3-proven) +
// acquire-spin; every reduction is distributed (48-block q, 192-block
// per-column combines, 192-block v). No block ever works alone.

#define H 768
#define H4 192
#define PSTRIDE 772   // partial: [0]=m, [1]=L, [2..3]=pad, [4..772)=acc[768]
#define ACC_OFF 4
#define NBLK 256      // blocks in both kernels (1/CU -> co-resident)
#define NQ 48         // q split-k blocks (16 k's each)
#define NCOL 192      // per-column combine blocks (768/4)

__device__ __forceinline__ float wave_max(float x) {
#pragma unroll
  for (int o = 32; o; o >>= 1) x = fmaxf(x, __shfl_xor(x, o, 64));
  return x;
}
__device__ __forceinline__ float wave_sum(float x) {
#pragma unroll
  for (int o = 32; o; o >>= 1) x += __shfl_xor(x, o, 64);
  return x;
}
__device__ __forceinline__ float4 f4max(float4 a, float4 b) {
  return make_float4(fmaxf(a.x, b.x), fmaxf(a.y, b.y), fmaxf(a.z, b.z), fmaxf(a.w, b.w));
}

struct SMem {
  float4 sacc[8][H4];  // 24.6 KB wave partials
  float sred[16];
  float4 swv[8];
};

// arrival: partial stores drained by __syncthreads (emits vmcnt(0) before
// barrier), release fence, device-scope count. Proven R3-R6.
__device__ __forceinline__ void arrive(unsigned int* c) {
  __syncthreads();
  if (threadIdx.x == 0) {
    __threadfence();
    atomicAdd(c, 1u);
  }
}
// consumer spin: acquire atomic load + s_sleep backoff; fence so all threads'
// subsequent plain loads see released data.
__device__ __forceinline__ void spin(unsigned int* c, unsigned int tgt) {
  if (threadIdx.x == 0) {
    while (__hip_atomic_load(c, __ATOMIC_ACQUIRE, __HIP_MEMORY_SCOPE_AGENT) < tgt)
      __builtin_amdgcn_s_sleep(32);
  }
  __syncthreads();
  __threadfence();
}

// wave-state (mrun,l,acc) -> merged block partial at part[blockIdx.x]
__device__ __forceinline__ void block_partial_store(SMem& sm, float* __restrict__ part,
                                                    float mrun, float l,
                                                    const float4 acc[3]) {
  const int tid = threadIdx.x, lane = tid & 63, wv = tid >> 6;
  if (lane == 0) { sm.sred[wv] = mrun; sm.sred[8 + wv] = l; }
#pragma unroll
  for (int j = 0; j < 3; ++j) sm.sacc[wv][lane + 64 * j] = acc[j];
  __syncthreads();
  if (wv == 0) {
    float gm = -INFINITY;
#pragma unroll
    for (int w2 = 0; w2 < 8; ++w2) gm = fmaxf(gm, sm.sred[w2]);
    float fa[8];
    float L = 0.f;
#pragma unroll
    for (int w2 = 0; w2 < 8; ++w2) {
      const float lw = sm.sred[8 + w2];
      fa[w2] = (lw > 0.f) ? __expf(sm.sred[w2] - gm) : 0.f;
      L = fmaf(fa[w2], lw, L);
    }
    float* pb = part + (size_t)blockIdx.x * PSTRIDE;
#pragma unroll
    for (int j = 0; j < 3; ++j) {
      float4 a = make_float4(0.f, 0.f, 0.f, 0.f);
#pragma unroll
      for (int w2 = 0; w2 < 8; ++w2) {
        const float4 t = sm.sacc[w2][lane + 64 * j];
        a.x = fmaf(fa[w2], t.x, a.x);
        a.y = fmaf(fa[w2], t.y, a.y);
        a.z = fmaf(fa[w2], t.z, a.z);
        a.w = fmaf(fa[w2], t.w, a.w);
      }
      *(float4*)(pb + ACC_OFF + 4 * (lane + 64 * j)) = a;
    }
    if (lane == 0) { pb[0] = gm; pb[1] = L; }
  }
}

// distributed combine: this block produces float4 column c over NBLK partials.
// thread t<NBLK loads partial t's (m,L,acc[c]); block-reduce. ~6KB, parallel.
__device__ __forceinline__ void col_combine(SMem& sm, const float* __restrict__ P,
                                            int c, float4* __restrict__ dA,
                                            float4* __restrict__ dB) {
  const int tid = threadIdx.x, lane = tid & 63, wv = tid >> 6;
  float m = -INFINITY, Lb = 0.f;
  float4 a = make_float4(0.f, 0.f, 0.f, 0.f);
  if (tid < NBLK) {
    const float* pb = P + (size_t)tid * PSTRIDE;
    m = pb[0];
    Lb = pb[1];
    a = *(const float4*)(pb + ACC_OFF + 4 * c);
  }
  float gm = wave_max(m);
  if (lane == 0) sm.sred[wv] = gm;
  __syncthreads();
  gm = sm.sred[0];
#pragma unroll
  for (int w2 = 1; w2 < 8; ++w2) gm = fmaxf(gm, sm.sred[w2]);
  __syncthreads();
  const float e = (Lb > 0.f) ? __expf(m - gm) : 0.f;
  float L = e * Lb;
  a.x *= e; a.y *= e; a.z *= e; a.w *= e;
  L = wave_sum(L);
  a.x = wave_sum(a.x); a.y = wave_sum(a.y);
  a.z = wave_sum(a.z); a.w = wave_sum(a.w);
  if (lane == 0) { sm.sred[8 + wv] = L; sm.swv[wv] = a; }
  __syncthreads();
  if (tid == 0) {
    float Lt = 0.f;
    float4 s = make_float4(0.f, 0.f, 0.f, 0.f);
#pragma unroll
    for (int w2 = 0; w2 < 8; ++w2) {
      Lt += sm.sred[8 + w2];
      const float4 t = sm.swv[w2];
      s.x += t.x; s.y += t.y; s.z += t.z; s.w += t.w;
    }
    const float inv = 1.f / Lt;
    const float4 r = make_float4(s.x * inv, s.y * inv, s.z * inv, s.w * inv);
    dA[c] = r;
    if (dB) dB[c] = r;
  }
}

// --- K1: colmax partials over fact; block 0 zeroes counters + q.
__global__ __launch_bounds__(192) void k_colmax(const float4* __restrict__ x4,
                                                float4* __restrict__ pmax4, int N,
                                                unsigned int* __restrict__ cnts,
                                                float* __restrict__ q) {
  const int t = threadIdx.x;
  if (blockIdx.x == 0) {
    if (t < 8) cnts[t] = 0u;
#pragma unroll
    for (int j = 0; j < 4; ++j) q[t + 192 * j] = 0.f;
  }
  const int rpb = (N + NBLK - 1) / NBLK;  // 128
  const int n0 = blockIdx.x * rpb;
  const int n1 = min(N, n0 + rpb);
  float4 m = make_float4(-INFINITY, -INFINITY, -INFINITY, -INFINITY);
#pragma unroll 8
  for (int n = n0; n < n1; ++n) m = f4max(m, x4[(size_t)n * H4 + t]);
  pmax4[(size_t)blockIdx.x * H4 + t] = m;
}

// --- K2: everything else, phase-flagged. cnts: [0]=q, [1]=ep, [2]=epcol,
// [3]=v, [4]=fact.
__global__ __launch_bounds__(512) void k_mega(
    const float4* __restrict__ fact4, const float4* __restrict__ ep4,
    const float4* __restrict__ W4, const float* __restrict__ pmax,
    float* __restrict__ q, float* __restrict__ epws, float* __restrict__ v,
    float* __restrict__ pm, float* __restrict__ pn, float* __restrict__ out,
    unsigned int* __restrict__ cnts, int N, int M) {
  const int tid = threadIdx.x, lane = tid & 63, wv = tid >> 6;
  const int blk = blockIdx.x;
  __shared__ SMem sm;
  __shared__ float sA[32][16];
  __shared__ float fQl[16];

  // ---- preload this wave's ep rows (independent of q -> overlaps P1)
  const int nw = NBLK * 8;
  const int gw = blk * 8 + wv;
  const int rpwM = (M + nw - 1) / nw;  // 2 at M=4096
  const int r0 = gw * rpwM, r1 = min(M, r0 + rpwM);
  const int npre = min(r1 - r0, 2);
  float4 xrow[2][3];
  for (int i = 0; i < npre; ++i) {
    const float4* row = ep4 + (size_t)(r0 + i) * H4;
#pragma unroll
    for (int j = 0; j < 3; ++j) xrow[i][j] = row[lane + 64 * j];
  }

  // ---- P1: q = fQ^T W, split-k over 48 blocks (block owns k in [16b,16b+16))
  if (blk < NQ) {
    const int k0 = blk * 16;
    const int col = tid & 15, grp = tid >> 4;  // 32 groups x 16 cols
    float m = -INFINITY;
    for (int p = grp; p < NBLK; p += 32) m = fmaxf(m, pmax[(size_t)p * H + k0 + col]);
    sA[grp][col] = m;
    __syncthreads();
    if (tid < 16) {
      float mm = sA[0][tid];
#pragma unroll
      for (int g = 1; g < 32; ++g) mm = fmaxf(mm, sA[g][tid]);
      fQl[tid] = mm;
    }
    __syncthreads();
    if (tid < H4) {
      float4 acc = make_float4(0.f, 0.f, 0.f, 0.f);
#pragma unroll 4
      for (int kk = 0; kk < 16; ++kk) {
        const float f = fQl[kk];
        const float4 w = W4[(size_t)(k0 + kk) * H4 + tid];
        acc.x = fmaf(f, w.x, acc.x);
        acc.y = fmaf(f, w.y, acc.y);
        acc.z = fmaf(f, w.z, acc.z);
        acc.w = fmaf(f, w.w, acc.w);
      }
      atomicAdd(&q[4 * tid + 0], acc.x);
      atomicAdd(&q[4 * tid + 1], acc.y);
      atomicAdd(&q[4 * tid + 2], acc.z);
      atomicAdd(&q[4 * tid + 3], acc.w);
    }
    arrive(cnts + 0);
  }
  spin(cnts + 0, NQ);

  // ---- P2: ep online-softmax (scores ep@q) -> block partial
  {
    float4 wr[3];
#pragma unroll
    for (int j = 0; j < 3; ++j) wr[j] = ((const float4*)q)[lane + 64 * j];
    float mrun = -INFINITY, l = 0.f;
    float4 acc[3];
#pragma unroll
    for (int j = 0; j < 3; ++j) acc[j] = make_float4(0.f, 0.f, 0.f, 0.f);
    for (int i = 0; i < npre; ++i) {
      float s = 0.f;
#pragma unroll
      for (int j = 0; j < 3; ++j) {
        s = fmaf(xrow[i][j].x, wr[j].x, s);
        s = fmaf(xrow[i][j].y, wr[j].y, s);
        s = fmaf(xrow[i][j].z, wr[j].z, s);
        s = fmaf(xrow[i][j].w, wr[j].w, s);
      }
      s = wave_sum(s);
      const float mn = fmaxf(mrun, s);
      const float esc = __expf(mrun - mn);
      const float p = __expf(s - mn);
      l = fmaf(l, esc, p);
#pragma unroll
      for (int j = 0; j < 3; ++j) {
        acc[j].x = fmaf(acc[j].x, esc, p * xrow[i][j].x);
        acc[j].y = fmaf(acc[j].y, esc, p * xrow[i][j].y);
        acc[j].z = fmaf(acc[j].z, esc, p * xrow[i][j].z);
        acc[j].w = fmaf(acc[j].w, esc, p * xrow[i][j].w);
      }
      mrun = mn;
    }
    for (int r = r0 + npre; r < r1; ++r) {  // generic tail (empty at M=4096)
      const float4* row = ep4 + (size_t)r * H4;
      float4 x[3];
      float s = 0.f;
#pragma unroll
      for (int j = 0; j < 3; ++j) {
        x[j] = row[lane + 64 * j];
        s = fmaf(x[j].x, wr[j].x, s);
        s = fmaf(x[j].y, wr[j].y, s);
        s = fmaf(x[j].z, wr[j].z, s);
        s = fmaf(x[j].w, wr[j].w, s);
      }
      s = wave_sum(s);
      const float mn = fmaxf(mrun, s);
      const float esc = __expf(mrun - mn);
      const float p = __expf(s - mn);
      l = fmaf(l, esc, p);
#pragma unroll
      for (int j = 0; j < 3; ++j) {
        acc[j].x = fmaf(acc[j].x, esc, p * x[j].x);
        acc[j].y = fmaf(acc[j].y, esc, p * x[j].y);
        acc[j].z = fmaf(acc[j].z, esc, p * x[j].z);
        acc[j].w = fmaf(acc[j].w, esc, p * x[j].w);
      }
      mrun = mn;
    }
    block_partial_store(sm, pm, mrun, l, acc);
  }
  arrive(cnts + 1);

  // ---- P3: distributed combine -> elements_p_ (epws + out[H..2H))
  spin(cnts + 1, NBLK);
  if (blk < NCOL) {
    col_combine(sm, pm, blk, (float4*)epws, (float4*)(out + H));
    arrive(cnts + 2);
  }
  spin(cnts + 2, NCOL);

  // ---- P4: v rows [4*blk, 4*blk+4): waves 0..3, one W row each
  if (blk < NCOL) {
    float4 er[3];
#pragma unroll
    for (int j = 0; j < 3; ++j) er[j] = ((const float4*)epws)[lane + 64 * j];
    if (wv < 4) {
      const int row = 4 * blk + wv;
      float s = 0.f;
#pragma unroll
      for (int j = 0; j < 3; ++j) {
        const float4 w = W4[(size_t)row * H4 + lane + 64 * j];
        s = fmaf(w.x, er[j].x, s);
        s = fmaf(w.y, er[j].y, s);
        s = fmaf(w.z, er[j].z, s);
        s = fmaf(w.w, er[j].w, s);
      }
      s = wave_sum(s);
      if (lane == 0) v[row] = s;
    }
    arrive(cnts + 3);
  }
  spin(cnts + 3, NCOL);

  // ---- P5: fact online-softmax (scores fact@v; fact L3-resident) -> partial
  {
    float4 vr[3];
#pragma unroll
    for (int j = 0; j < 3; ++j) vr[j] = ((const float4*)v)[lane + 64 * j];
    const int rpwN = (N + nw - 1) / nw;  // 16
    const int f0 = gw * rpwN, f1 = min(N, f0 + rpwN);
    float mrun = -INFINITY, l = 0.f;
    float4 acc[3];
#pragma unroll
    for (int j = 0; j < 3; ++j) acc[j] = make_float4(0.f, 0.f, 0.f, 0.f);
    for (int r = f0; r < f1; ++r) {
      const float4* row = fact4 + (size_t)r * H4;
      float4 x[3];
      float s = 0.f;
#pragma unroll
      for (int j = 0; j < 3; ++j) {
        x[j] = row[lane + 64 * j];
        s = fmaf(x[j].x, vr[j].x, s);
        s = fmaf(x[j].y, vr[j].y, s);
        s = fmaf(x[j].z, vr[j].z, s);
        s = fmaf(x[j].w, vr[j].w, s);
      }
      s = wave_sum(s);
      const float mn = fmaxf(mrun, s);
      const float esc = __expf(mrun - mn);
      const float p = __expf(s - mn);
      l = fmaf(l, esc, p);
#pragma unroll
      for (int j = 0; j < 3; ++j) {
        acc[j].x = fmaf(acc[j].x, esc, p * x[j].x);
        acc[j].y = fmaf(acc[j].y, esc, p * x[j].y);
        acc[j].z = fmaf(acc[j].z, esc, p * x[j].z);
        acc[j].w = fmaf(acc[j].w, esc, p * x[j].w);
      }
      mrun = mn;
    }
    block_partial_store(sm, pn, mrun, l, acc);
  }
  arrive(cnts + 4);

  // ---- P6: distributed combine -> fact_ (out[0..H))
  spin(cnts + 4, NBLK);
  if (blk < NCOL) col_combine(sm, pn, blk, (float4*)out, nullptr);
}

extern "C" void kernel_launch(void* const* d_in, const int* in_sizes, int n_in,
                              void* d_out, int out_size, void* d_ws, size_t ws_size,
                              hipStream_t stream) {
  const float4* fact4 = (const float4*)d_in[0];  // [N,H]
  const float4* ep4   = (const float4*)d_in[1];  // [M,H]
  const float4* W4    = (const float4*)d_in[2];  // [H,H]
  float* out = (float*)d_out;
  const int N = in_sizes[0] / H;
  const int M = in_sizes[1] / H;

  float* wsf = (float*)d_ws;
  unsigned int* cnts = (unsigned int*)d_ws;        // 8 uints (32 B)
  float* q    = wsf + 8;                           // 768, 16B-aligned
  float* epws = wsf + 8 + H;                       // 768
  float* v    = wsf + 8 + 2 * H;                   // 768
  float* pmaxf = wsf + 8 + 3 * H;                  // NBLK*768
  float* pm   = pmaxf + (size_t)NBLK * H;          // NBLK*772
  float* pn   = pm + (size_t)NBLK * PSTRIDE;       // NBLK*772

  k_colmax<<<NBLK, 192, 0, stream>>>(fact4, (float4*)pmaxf, N, cnts, q);
  k_mega<<<NBLK, 512, 0, stream>>>(fact4, ep4, W4, pmaxf, q, epws, v, pm, pn,
                                   out, cnts, N, M);
}

// Round 8
// 222.626 us; speedup vs baseline: 1.9354x; 1.9354x over previous
//
#include <hip/hip_runtime.h>
#include <math.h>

// N=32768, M=4096, H=768 fp32.
// out[0..768)=fact_, out[768..1536)=elements_p_.
// Reassociation: (X@W)@y^T == X@(W@y^T) -> matvecs only, never a GEMM.
// Session model (R2-R7): harness-fixed ~120us, ~8.5us/graph-node gap,
// single-CU gathers ~25us/MB, wide (>100-block) counter spins catastrophic
// (~40us each, R7), narrow (<=8-poller) spins fine.
// R8: 5 nodes, zero wide syncs: colmax(+zero) -> k_q -> k_ep(pure stream) ->
// k_epcomb_v(192-block per-column combine + v atomics) -> k_fact(+last-8 tail).

#define H 768
#define H4 192
#define PSTRIDE 772   // partial: [0]=m, [1]=L, [2..3]=pad, [4..772)=acc[768]
#define ACC_OFF 4
#define NBLK 256      // stream blocks (1/CU)
#define NQ 48         // k_q blocks
#define NCOL 192      // per-column combine blocks

__device__ __forceinline__ float wave_max(float x) {
#pragma unroll
  for (int o = 32; o; o >>= 1) x = fmaxf(x, __shfl_xor(x, o, 64));
  return x;
}
__device__ __forceinline__ float wave_sum(float x) {
#pragma unroll
  for (int o = 32; o; o >>= 1) x += __shfl_xor(x, o, 64);
  return x;
}
__device__ __forceinline__ float4 f4max(float4 a, float4 b) {
  return make_float4(fmaxf(a.x, b.x), fmaxf(a.y, b.y), fmaxf(a.z, b.z), fmaxf(a.w, b.w));
}

struct SMem {
  float4 sacc[8][H4];  // 24.6 KB wave partials
  float sred[16];
};

// ---- online-softmax weighted row-sum stream -> block partial (R6-proven)
__device__ __forceinline__ void stream_pass(const float4* __restrict__ X4,
                                            const float* __restrict__ wvec,
                                            float* __restrict__ part, int R,
                                            SMem& sm) {
  const int tid = threadIdx.x, lane = tid & 63, wv = tid >> 6;
  float4 wr[3];
#pragma unroll
  for (int j = 0; j < 3; ++j) wr[j] = ((const float4*)wvec)[lane + 64 * j];
  const int nw = NBLK * 8;
  const int gw = blockIdx.x * 8 + wv;
  const int rpw = (R + nw - 1) / nw;
  const int r0 = gw * rpw;
  const int r1 = min(R, r0 + rpw);
  float mrun = -INFINITY, l = 0.f;
  float4 acc[3];
#pragma unroll
  for (int j = 0; j < 3; ++j) acc[j] = make_float4(0.f, 0.f, 0.f, 0.f);
  for (int r = r0; r < r1; ++r) {
    const float4* row = X4 + (size_t)r * H4;
    float4 x[3];
    float s = 0.f;
#pragma unroll
    for (int j = 0; j < 3; ++j) {
      x[j] = row[lane + 64 * j];
      s = fmaf(x[j].x, wr[j].x, s);
      s = fmaf(x[j].y, wr[j].y, s);
      s = fmaf(x[j].z, wr[j].z, s);
      s = fmaf(x[j].w, wr[j].w, s);
    }
    s = wave_sum(s);
    const float mn = fmaxf(mrun, s);
    const float esc = __expf(mrun - mn);  // exp(-inf)=0 on first row
    const float p = __expf(s - mn);
    l = fmaf(l, esc, p);
#pragma unroll
    for (int j = 0; j < 3; ++j) {
      acc[j].x = fmaf(acc[j].x, esc, p * x[j].x);
      acc[j].y = fmaf(acc[j].y, esc, p * x[j].y);
      acc[j].z = fmaf(acc[j].z, esc, p * x[j].z);
      acc[j].w = fmaf(acc[j].w, esc, p * x[j].w);
    }
    mrun = mn;
  }
  if (lane == 0) { sm.sred[wv] = mrun; sm.sred[8 + wv] = l; }
#pragma unroll
  for (int j = 0; j < 3; ++j) sm.sacc[wv][lane + 64 * j] = acc[j];
  __syncthreads();
  if (wv == 0) {
    float gm = -INFINITY;
#pragma unroll
    for (int w2 = 0; w2 < 8; ++w2) gm = fmaxf(gm, sm.sred[w2]);
    float fa[8];
    float L = 0.f;
#pragma unroll
    for (int w2 = 0; w2 < 8; ++w2) {
      const float lw = sm.sred[8 + w2];
      fa[w2] = (lw > 0.f) ? __expf(sm.sred[w2] - gm) : 0.f;
      L = fmaf(fa[w2], lw, L);
    }
    float* pb = part + (size_t)blockIdx.x * PSTRIDE;
#pragma unroll
    for (int j = 0; j < 3; ++j) {
      float4 a = make_float4(0.f, 0.f, 0.f, 0.f);
#pragma unroll
      for (int w2 = 0; w2 < 8; ++w2) {
        const float4 t = sm.sacc[w2][lane + 64 * j];
        a.x = fmaf(fa[w2], t.x, a.x);
        a.y = fmaf(fa[w2], t.y, a.y);
        a.z = fmaf(fa[w2], t.z, a.z);
        a.w = fmaf(fa[w2], t.w, a.w);
      }
      *(float4*)(pb + ACC_OFF + 4 * (lane + 64 * j)) = a;
    }
    if (lane == 0) { pb[0] = gm; pb[1] = L; }
  }
}

// --- N1: colmax partials over fact; block 0 zeroes counters + q + v.
__global__ __launch_bounds__(192) void k_colmax(const float4* __restrict__ x4,
                                                float4* __restrict__ pmax4, int N,
                                                unsigned int* __restrict__ cnts,
                                                float* __restrict__ q,
                                                float* __restrict__ v) {
  const int t = threadIdx.x;
  if (blockIdx.x == 0) {
    if (t < 8) cnts[t] = 0u;
#pragma unroll
    for (int j = 0; j < 4; ++j) { q[t + 192 * j] = 0.f; v[t + 192 * j] = 0.f; }
  }
  const int rpb = (N + NBLK - 1) / NBLK;  // 128
  const int n0 = blockIdx.x * rpb;
  const int n1 = min(N, n0 + rpb);
  float4 m = make_float4(-INFINITY, -INFINITY, -INFINITY, -INFINITY);
#pragma unroll 8
  for (int n = n0; n < n1; ++n) m = f4max(m, x4[(size_t)n * H4 + t]);
  pmax4[(size_t)blockIdx.x * H4 + t] = m;
}

// --- N2: split-k q. Block b owns k in [16b,16b+16): reduce those pmax cols,
// q[h] += sum_k fQ[k]*W[k,h] via atomicAdd. (R3/R6-proven, ~3us.)
__global__ __launch_bounds__(192) void k_q(const float4* __restrict__ W4,
                                           const float* __restrict__ pmax,
                                           float* __restrict__ q) {
  const int tid = threadIdx.x;
  const int k0 = blockIdx.x * 16;
  __shared__ float sA[12][16];
  __shared__ float fQl[16];
  {
    const int col = tid & 15;
    const int grp = tid >> 4;  // 0..11
    float m = -INFINITY;
    for (int p = grp; p < NBLK; p += 12) m = fmaxf(m, pmax[(size_t)p * H + k0 + col]);
    sA[grp][col] = m;
    __syncthreads();
    if (tid < 16) {
      float mm = sA[0][tid];
#pragma unroll
      for (int g = 1; g < 12; ++g) mm = fmaxf(mm, sA[g][tid]);
      fQl[tid] = mm;
    }
    __syncthreads();
  }
  float4 acc = make_float4(0.f, 0.f, 0.f, 0.f);
#pragma unroll 4
  for (int kk = 0; kk < 16; ++kk) {
    const float f = fQl[kk];
    const float4 w = W4[(size_t)(k0 + kk) * H4 + tid];
    acc.x = fmaf(f, w.x, acc.x);
    acc.y = fmaf(f, w.y, acc.y);
    acc.z = fmaf(f, w.z, acc.z);
    acc.w = fmaf(f, w.w, acc.w);
  }
  atomicAdd(&q[4 * tid + 0], acc.x);
  atomicAdd(&q[4 * tid + 1], acc.y);
  atomicAdd(&q[4 * tid + 2], acc.z);
  atomicAdd(&q[4 * tid + 3], acc.w);
}

// --- N3: ep stream (scores ep@q) -> 256 partials. Pure stream, no tail.
__global__ __launch_bounds__(512) void k_ep(const float4* __restrict__ ep4,
                                            const float* __restrict__ q,
                                            float* __restrict__ pm, int M) {
  __shared__ SMem sm;
  stream_pass(ep4, q, pm, M, sm);
}

// --- N4: per-column combine of ep partials -> elements_p_ column c=blk
// (write out+H), then v[i] += W[i,4c..4c+4) . ep_[4c..4c+4) for all i
// (atomicAdd; each block only needs ITS OWN column -> no cross-block dep).
__global__ __launch_bounds__(512) void k_epcomb_v(const float* __restrict__ P,
                                                  const float4* __restrict__ W4,
                                                  float4* __restrict__ out_ep,
                                                  float* __restrict__ v) {
  const int tid = threadIdx.x, lane = tid & 63, wv = tid >> 6;
  const int c = blockIdx.x;
  __shared__ float sred[16];
  __shared__ float4 swv[8];
  __shared__ float4 sr4;
  float m = -INFINITY, Lb = 0.f;
  float4 a = make_float4(0.f, 0.f, 0.f, 0.f);
  if (tid < NBLK) {
    const float* pb = P + (size_t)tid * PSTRIDE;
    m = pb[0];
    Lb = pb[1];
    a = *(const float4*)(pb + ACC_OFF + 4 * c);
  }
  float gm = wave_max(m);
  if (lane == 0) sred[wv] = gm;
  __syncthreads();
  gm = sred[0];
#pragma unroll
  for (int w2 = 1; w2 < 8; ++w2) gm = fmaxf(gm, sred[w2]);
  __syncthreads();
  const float e = (Lb > 0.f) ? __expf(m - gm) : 0.f;
  float L = e * Lb;
  a.x *= e; a.y *= e; a.z *= e; a.w *= e;
  L = wave_sum(L);
  a.x = wave_sum(a.x); a.y = wave_sum(a.y);
  a.z = wave_sum(a.z); a.w = wave_sum(a.w);
  if (lane == 0) { sred[8 + wv] = L; swv[wv] = a; }
  __syncthreads();
  if (tid == 0) {
    float Lt = 0.f;
    float4 s = make_float4(0.f, 0.f, 0.f, 0.f);
#pragma unroll
    for (int w2 = 0; w2 < 8; ++w2) {
      Lt += sred[8 + w2];
      const float4 t = swv[w2];
      s.x += t.x; s.y += t.y; s.z += t.z; s.w += t.w;
    }
    const float inv = 1.f / Lt;
    const float4 r = make_float4(s.x * inv, s.y * inv, s.z * inv, s.w * inv);
    out_ep[c] = r;
    sr4 = r;
  }
  __syncthreads();
  const float4 r4 = sr4;
  for (int i = tid; i < H; i += 512) {
    const float4 w = W4[(size_t)i * H4 + c];
    const float s = fmaf(w.x, r4.x, fmaf(w.y, r4.y, fmaf(w.z, r4.z, w.w * r4.w)));
    atomicAdd(&v[i], s);
  }
}

// --- N5: fact stream (scores fact@v; fact L3-resident) + narrow hierarchical
// tail: last-8-ranked blocks (<=8 pollers: safe) combine 32 partials each;
// 8th stage-B arriver merges 8 -> out[0..768).
__global__ __launch_bounds__(512) void k_fact(const float4* __restrict__ X4,
                                              const float* __restrict__ v,
                                              float* __restrict__ pn,
                                              float* __restrict__ pn2, int R,
                                              unsigned int* __restrict__ cntA,
                                              unsigned int* __restrict__ cntB,
                                              float* __restrict__ outp) {
  const int tid = threadIdx.x, lane = tid & 63, wv = tid >> 6;
  __shared__ SMem sm;
  stream_pass(X4, v, pn, R, sm);

  // ---- arrive (syncthreads drains vmcnt before barrier; release fence)
  __shared__ unsigned int s_rank;
  __syncthreads();
  if (tid == 0) {
    __threadfence();
    s_rank = atomicAdd(cntA, 1u);
  }
  __syncthreads();
  const unsigned int rank = s_rank;
  if (rank < (unsigned)(NBLK - 8)) return;

  // narrow spin: at most 8 blocks polling, short skew wait
  if (tid == 0) {
    while (__hip_atomic_load(cntA, __ATOMIC_ACQUIRE, __HIP_MEMORY_SCOPE_AGENT) <
           (unsigned)NBLK)
      __builtin_amdgcn_s_sleep(8);
  }
  __syncthreads();
  __threadfence();

  // ---- stage A: combine 32 partials of our slice -> pn2[slice]
  const int slice = (int)rank - (NBLK - 8);
  const float* Pb = pn + (size_t)slice * 32 * PSTRIDE;
  __shared__ float s32m[32], s32l[32];
  if (tid < 32) {
    s32m[tid] = Pb[(size_t)tid * PSTRIDE];
    s32l[tid] = Pb[(size_t)tid * PSTRIDE + 1];
  }
  __syncthreads();
  float gms = -INFINITY;
#pragma unroll
  for (int b = 0; b < 32; ++b) gms = fmaxf(gms, s32m[b]);
  float4 a[3];
#pragma unroll
  for (int j = 0; j < 3; ++j) a[j] = make_float4(0.f, 0.f, 0.f, 0.f);
  for (int b = wv; b < 32; b += 8) {
    const float e = (s32l[b] > 0.f) ? __expf(s32m[b] - gms) : 0.f;
    const float4* pa = (const float4*)(Pb + (size_t)b * PSTRIDE + ACC_OFF);
#pragma unroll
    for (int j = 0; j < 3; ++j) {
      const float4 t = pa[lane + 64 * j];
      a[j].x = fmaf(e, t.x, a[j].x);
      a[j].y = fmaf(e, t.y, a[j].y);
      a[j].z = fmaf(e, t.z, a[j].z);
      a[j].w = fmaf(e, t.w, a[j].w);
    }
  }
  float lc = 0.f;
  if (tid < 32) lc = ((s32l[tid] > 0.f) ? __expf(s32m[tid] - gms) : 0.f) * s32l[tid];
  lc = wave_sum(lc);  // wave 0 holds the full sum
  __syncthreads();    // sacc reuse guard (stream_pass wrote it)
#pragma unroll
  for (int j = 0; j < 3; ++j) sm.sacc[wv][lane + 64 * j] = a[j];
  if (tid == 0) sm.sred[0] = lc;
  __syncthreads();
  float* qb = pn2 + (size_t)slice * PSTRIDE;
  if (tid < H4) {
    float4 s = sm.sacc[0][tid];
#pragma unroll
    for (int w2 = 1; w2 < 8; ++w2) {
      const float4 t = sm.sacc[w2][tid];
      s.x += t.x; s.y += t.y; s.z += t.z; s.w += t.w;
    }
    *(float4*)(qb + ACC_OFF + 4 * tid) = s;
  }
  if (tid == 0) { qb[0] = gms; qb[1] = sm.sred[0]; }

  // ---- stage B arrive: 8th arriver needs no spin (all 8 already released)
  __syncthreads();
  __shared__ unsigned int s_r2;
  if (tid == 0) {
    __threadfence();
    s_r2 = atomicAdd(cntB, 1u);
  }
  __syncthreads();
  if (s_r2 != 7u) return;
  __threadfence();

  // ---- final: merge 8 L2 partials -> out
  __shared__ float s8m[8], s8l[8];
  if (tid < 8) {
    s8m[tid] = pn2[(size_t)tid * PSTRIDE];
    s8l[tid] = pn2[(size_t)tid * PSTRIDE + 1];
  }
  __syncthreads();
  float gm = -INFINITY;
#pragma unroll
  for (int k = 0; k < 8; ++k) gm = fmaxf(gm, s8m[k]);
  float Lt = 0.f;
#pragma unroll
  for (int k = 0; k < 8; ++k)
    Lt += ((s8l[k] > 0.f) ? __expf(s8m[k] - gm) : 0.f) * s8l[k];
  float4 b[3];
  {
    const int k = wv;  // wave wv handles L2 partial wv
    const float e = (s8l[k] > 0.f) ? __expf(s8m[k] - gm) : 0.f;
    const float4* pa = (const float4*)(pn2 + (size_t)k * PSTRIDE + ACC_OFF);
#pragma unroll
    for (int j = 0; j < 3; ++j) {
      const float4 t = pa[lane + 64 * j];
      b[j] = make_float4(e * t.x, e * t.y, e * t.z, e * t.w);
    }
  }
  __syncthreads();  // sacc reuse guard
#pragma unroll
  for (int j = 0; j < 3; ++j) sm.sacc[wv][lane + 64 * j] = b[j];
  __syncthreads();
  if (tid < H4) {
    float4 s = sm.sacc[0][tid];
#pragma unroll
    for (int w2 = 1; w2 < 8; ++w2) {
      const float4 t = sm.sacc[w2][tid];
      s.x += t.x; s.y += t.y; s.z += t.z; s.w += t.w;
    }
    const float inv = 1.f / Lt;
    ((float4*)outp)[tid] = make_float4(s.x * inv, s.y * inv, s.z * inv, s.w * inv);
  }
}

extern "C" void kernel_launch(void* const* d_in, const int* in_sizes, int n_in,
                              void* d_out, int out_size, void* d_ws, size_t ws_size,
                              hipStream_t stream) {
  const float4* fact4 = (const float4*)d_in[0];  // [N,H]
  const float4* ep4   = (const float4*)d_in[1];  // [M,H]
  const float4* W4    = (const float4*)d_in[2];  // [H,H]
  float* out = (float*)d_out;
  const int N = in_sizes[0] / H;
  const int M = in_sizes[1] / H;

  float* wsf = (float*)d_ws;
  unsigned int* cnts = (unsigned int*)d_ws;        // 8 uints
  float* q     = wsf + 8;                          // 768 (32B-aligned)
  float* v     = wsf + 776;                        // 768
  float* pmaxf = wsf + 1544;                       // 256*768
  float* pm    = wsf + 198152;                     // 256*772 (ep partials)
  float* pn    = wsf + 395784;                     // 256*772 (fact partials)
  float* pn2   = wsf + 593416;                     // 8*772  (L2 partials)

  k_colmax<<<NBLK, 192, 0, stream>>>(fact4, (float4*)pmaxf, N, cnts, q, v);
  k_q<<<NQ, 192, 0, stream>>>(W4, pmaxf, q);
  k_ep<<<NBLK, 512, 0, stream>>>(ep4, q, pm, M);
  k_epcomb_v<<<NCOL, 512, 0, stream>>>(pm, W4, (float4*)(out + H), v);
  k_fact<<<NBLK, 512, 0, stream>>>(fact4, v, pn, pn2, N, cnts + 0, cnts + 1, out);
}